// Round 6
// baseline (182.339 us; speedup 1.0000x reference)
//
#include <hip/hip_runtime.h>

// InfluenceEncoder: B=4096, N=257, D=16, H=128.
// Kernel A: HALF-batch per wave (8192 waves), 32x32x16 f16 MFMA, depth-2
//   register pipeline on A-tiles (keeps VGPR < 128, no spill at (256,4)).
//   Weights computed per-tile from the A-tile regs (x,y at k=0,1; f6 at k=6),
//   staged in wave-private LDS (barrier-free), read back as broadcast w4.
//   relu-bias fold: relu(e+b) = max(e,-b)+b. Unnormalized f16 partials +
//   partial wsum to d_ws.
// Kernel B: 2048 waves; job = (16-row batch tile, 16-col tile).
//   renorm + bias + relu + f16-cvt fused into the A-frag path;
//   4x mfma_f32_16x16x32_f16 over K=128 vs Wagg^T; += bagg; fp32 out.

typedef _Float16 half_t;
typedef half_t f16x8 __attribute__((ext_vector_type(8)));
typedef float f32x4 __attribute__((ext_vector_type(4)));
typedef float f32x16 __attribute__((ext_vector_type(16)));

__global__ __launch_bounds__(256, 4) void agg_kernel(
    const float* __restrict__ x,     // [4096,257,16]
    const float* __restrict__ Wfc,   // [128,16]
    const float* __restrict__ bfc,   // [128]
    half_t* __restrict__ p_ws,       // [4096][2][128] f16 unnormalized partials
    float* __restrict__ s_ws)        // [4096][2] partial weight sums
{
    const int t    = threadIdx.x;
    const int lane = t & 63;
    const int wv   = t >> 6;
    const int W    = blockIdx.x * 4 + wv;
    const int b    = W >> 1;
    const int hf   = W & 1;
    const int lm   = lane & 31;   // row-in-tile (A) / col-in-tile (B,D)
    const int hi   = lane >> 5;   // k-octet

    __shared__ float wls[4][128];

    const float* xb = x + (size_t)b * (257 * 16);
    const int row0 = 1 + hf * 128;

    // ---- B-frags (Wfc) + folded -bias ----
    f16x8 bfr[4];
    float nb[4];
    #pragma unroll
    for (int ct = 0; ct < 4; ++ct) {
        const float* wp = Wfc + (size_t)(ct * 32 + lm) * 16 + hi * 8;
        const float4 w0 = *(const float4*)wp;
        const float4 w1 = *(const float4*)(wp + 4);
        bfr[ct] = (f16x8){(half_t)w0.x, (half_t)w0.y, (half_t)w0.z, (half_t)w0.w,
                          (half_t)w1.x, (half_t)w1.y, (half_t)w1.z, (half_t)w1.w};
        nb[ct] = -bfc[ct * 32 + lm];
    }
    const float2 ego = *(const float2*)xb;

    // ---- depth-2 pipelined A-tiles (4 tiles of 32 agents) ----
    float4 s0[2], s1[2];
    #pragma unroll
    for (int i = 0; i < 2; ++i) {
        const float* rp = xb + (size_t)(row0 + i * 32 + lm) * 16 + hi * 8;
        s0[i] = *(const float4*)rp;
        s1[i] = *(const float4*)(rp + 4);
    }

    float wsum = 0.f;
    float pacc[4] = {0.f, 0.f, 0.f, 0.f};

    #pragma unroll
    for (int tm = 0; tm < 4; ++tm) {
        const int cur = tm & 1;
        const float4 a0 = s0[cur], a1 = s1[cur];
        if (tm < 2) {
            const float* rp = xb + (size_t)(row0 + (tm + 2) * 32 + lm) * 16 + hi * 8;
            s0[cur] = *(const float4*)rp;
            s1[cur] = *(const float4*)(rp + 4);
        }
        // weights for this tile from in-flight regs (lo lanes: k=0..7)
        if (hi == 0) {
            const float dx = a0.x - ego.x, dy = a0.y - ego.y;
            float w = 1.0f / (sqrtf(dx * dx + dy * dy) + 1.0f);
            if (a1.z == 1.0f) w *= 5.0f;   // feature 6
            wls[wv][tm * 32 + lm] = w;
            wsum += w;
        }
        const f16x8 afr = (f16x8){(half_t)a0.x, (half_t)a0.y, (half_t)a0.z, (half_t)a0.w,
                                  (half_t)a1.x, (half_t)a1.y, (half_t)a1.z, (half_t)a1.w};
        // broadcast read-back of this tile's 32 weights (same-wave DS order)
        float4 w4[4];
        #pragma unroll
        for (int q = 0; q < 4; ++q)
            w4[q] = *(const float4*)(&wls[wv][tm * 32 + q * 8 + hi * 4]);
        #pragma unroll
        for (int ct = 0; ct < 4; ++ct) {
            f32x16 zc = {};
            const f32x16 d = __builtin_amdgcn_mfma_f32_32x32x16_f16(afr, bfr[ct], zc, 0, 0, 0);
            // D layout: col=lane&31, row=(r&3)+8*(r>>2)+4*hi
            #pragma unroll
            for (int r = 0; r < 16; ++r)
                pacc[ct] = fmaf(w4[r >> 2][r & 3], fmaxf(d[r], nb[ct]), pacc[ct]);
        }
    }

    // ---- combine k-octet halves, store f16 partials ----
    #pragma unroll
    for (int ct = 0; ct < 4; ++ct) pacc[ct] += __shfl_xor(pacc[ct], 32);
    #pragma unroll
    for (int off = 32; off > 0; off >>= 1) wsum += __shfl_xor(wsum, off);
    if (hi == 0) {
        half_t* pp = p_ws + ((size_t)b * 2 + hf) * 128;
        #pragma unroll
        for (int ct = 0; ct < 4; ++ct) pp[ct * 32 + lm] = (half_t)pacc[ct];
        if (lane == 0) s_ws[b * 2 + hf] = wsum;
    }
}

__global__ __launch_bounds__(256, 4) void out_kernel(
    const half_t* __restrict__ p_ws, // [4096][2][128] f16
    const float* __restrict__ s_ws,  // [4096][2]
    const float* __restrict__ bfc,   // [128]
    const float* __restrict__ Wagg,  // [128,128]
    const float* __restrict__ bagg,  // [128]
    float* __restrict__ out)         // [4096,128]
{
    const int t    = threadIdx.x;
    const int lane = t & 63;
    const int wv   = t >> 6;
    const int j    = blockIdx.x * 4 + wv;  // 0..2047
    const int mt   = j >> 3;               // batch tile (16 rows)
    const int ct   = j & 7;                // col tile (16 cols)
    const int lr   = lane & 15;
    const int lq   = lane >> 4;

    const int brow = mt * 16 + lr;
    const float2 s2 = *(const float2*)(s_ws + brow * 2);
    const float inv = 1.0f / (s2.x + s2.y + 1e-10f);

    const int col = ct * 16 + lr;
    const float bb = bagg[col];
    f32x4 acc = (f32x4){bb, bb, bb, bb};

    const half_t* pb  = p_ws + (size_t)brow * 256;
    const float* wrow = Wagg + (size_t)col * 128;

    #pragma unroll
    for (int kk = 0; kk < 4; ++kk) {
        const int k0 = kk * 32 + lq * 8;
        const f16x8 p0 = *(const f16x8*)(pb + k0);
        const f16x8 p1 = *(const f16x8*)(pb + 128 + k0);
        const float4 bf0 = *(const float4*)(bfc + k0);
        const float4 bf1 = *(const float4*)(bfc + k0 + 4);
        // e = relu((p0+p1)*inv + bfc): renorm + bias + relu fused
        const f16x8 afr = (f16x8){
            (half_t)fmaxf(fmaf((float)p0[0] + (float)p1[0], inv, bf0.x), 0.f),
            (half_t)fmaxf(fmaf((float)p0[1] + (float)p1[1], inv, bf0.y), 0.f),
            (half_t)fmaxf(fmaf((float)p0[2] + (float)p1[2], inv, bf0.z), 0.f),
            (half_t)fmaxf(fmaf((float)p0[3] + (float)p1[3], inv, bf0.w), 0.f),
            (half_t)fmaxf(fmaf((float)p0[4] + (float)p1[4], inv, bf1.x), 0.f),
            (half_t)fmaxf(fmaf((float)p0[5] + (float)p1[5], inv, bf1.y), 0.f),
            (half_t)fmaxf(fmaf((float)p0[6] + (float)p1[6], inv, bf1.z), 0.f),
            (half_t)fmaxf(fmaf((float)p0[7] + (float)p1[7], inv, bf1.w), 0.f)};
        const float4 wg0 = *(const float4*)(wrow + k0);
        const float4 wg1 = *(const float4*)(wrow + k0 + 4);
        const f16x8 bfr = (f16x8){(half_t)wg0.x, (half_t)wg0.y, (half_t)wg0.z, (half_t)wg0.w,
                                  (half_t)wg1.x, (half_t)wg1.y, (half_t)wg1.z, (half_t)wg1.w};
        acc = __builtin_amdgcn_mfma_f32_16x16x32_f16(afr, bfr, acc, 0, 0, 0);
    }

    // D: col=lane&15, row=lq*4+jj
    #pragma unroll
    for (int jj = 0; jj < 4; ++jj)
        out[(size_t)(mt * 16 + lq * 4 + jj) * 128 + col] = acc[jj];
}

extern "C" void kernel_launch(void* const* d_in, const int* in_sizes, int n_in,
                              void* d_out, int out_size, void* d_ws, size_t ws_size,
                              hipStream_t stream) {
    const float* x    = (const float*)d_in[0];
    const float* Wfc  = (const float*)d_in[1];
    const float* bfc  = (const float*)d_in[2];
    const float* Wagg = (const float*)d_in[3];
    const float* bagg = (const float*)d_in[4];
    float* out = (float*)d_out;

    half_t* p_ws = (half_t*)d_ws;                          // 4096*256 f16 = 2 MB
    float*  s_ws = (float*)((char*)d_ws + (size_t)4096 * 256 * sizeof(half_t));

    agg_kernel<<<dim3(2048), dim3(256), 0, stream>>>(x, Wfc, bfc, p_ws, s_ws);
    out_kernel<<<dim3(512), dim3(256), 0, stream>>>(p_ws, s_ws, bfc, Wagg, bagg, out);
}

// Round 7
// 30.995 us; speedup vs baseline: 5.8829x; 5.8829x over previous
//
#include <hip/hip_runtime.h>

// InfluenceEncoder: B=4096, N=257, D=16, H=128.
// Kernel A: HALF-batch per wave (8192 waves). 32x32x16 f16 MFMA (fast path).
//   Wave W: batch b=W>>1, half hf=W&1 (128 agents). 4 m-tiles x 4 col-tiles.
//   A-tiles all loaded up-front (coalesced float4 pairs); weights computed by
//   lo-half lanes from those regs (x,y at k=0,1; f6 at k=6) -> wave-private
//   LDS slice, barrier-free. relu-bias fold: relu(e+b)=max(e,-b)+b.
//   Unnormalized fp32 partials + partial wsum to d_ws.
//   REGISTER BUDGET: amdgpu_waves_per_eu(4,4) pins the allocator at 128 VGPR.
//   R5 lesson: launch_bounds(256,4) alone let the backend target 8 waves/EU
//   (64 VGPR) and spill ~650 MB of scratch -> 200 us.
// Kernel B: 2048 waves; job = (16-row batch tile, 16-col tile).
//   renorm+bias+relu+f16cvt fused into A-frag path; 4x mfma_f32_16x16x32_f16
//   over K=128 vs Wagg^T; += bagg; fp32 out.

typedef _Float16 half_t;
typedef half_t f16x8 __attribute__((ext_vector_type(8)));
typedef float f32x4 __attribute__((ext_vector_type(4)));
typedef float f32x16 __attribute__((ext_vector_type(16)));

__global__ __launch_bounds__(256)
__attribute__((amdgpu_waves_per_eu(4, 4)))
void agg_kernel(
    const float* __restrict__ x,     // [4096,257,16]
    const float* __restrict__ Wfc,   // [128,16]
    const float* __restrict__ bfc,   // [128]
    float* __restrict__ p_ws,        // [4096][2][128] unnormalized partials
    float* __restrict__ s_ws)        // [4096][2] partial weight sums
{
    const int t    = threadIdx.x;
    const int lane = t & 63;
    const int wv   = t >> 6;
    const int W    = blockIdx.x * 4 + wv;
    const int b    = W >> 1;
    const int hf   = W & 1;
    const int lm   = lane & 31;   // row-in-tile (A) / col-in-tile (B,D)
    const int hi   = lane >> 5;   // k-octet

    __shared__ float wls[4][128];

    const float* xb = x + (size_t)b * (257 * 16);
    const int row0 = 1 + hf * 128;

    // ---- A-tile loads: 4 tiles of 32 rows; lane -> row lm, k [hi*8, +8) ----
    float4 a0[4], a1[4];
    #pragma unroll
    for (int tm = 0; tm < 4; ++tm) {
        const float* rp = xb + (size_t)(row0 + tm * 32 + lm) * 16 + hi * 8;
        a0[tm] = *(const float4*)rp;
        a1[tm] = *(const float4*)(rp + 4);
    }

    // ---- B-frags: B[k=hi*8+j][col=ct*32+lm] = Wfc[ct*32+lm][hi*8+j] ----
    f16x8 bfr[4];
    #pragma unroll
    for (int ct = 0; ct < 4; ++ct) {
        const float* wp = Wfc + (size_t)(ct * 32 + lm) * 16 + hi * 8;
        const float4 w0 = *(const float4*)wp;
        const float4 w1 = *(const float4*)(wp + 4);
        bfr[ct] = (f16x8){(half_t)w0.x, (half_t)w0.y, (half_t)w0.z, (half_t)w0.w,
                          (half_t)w1.x, (half_t)w1.y, (half_t)w1.z, (half_t)w1.w};
    }

    float nb[4];   // -bias for relu-fold
    #pragma unroll
    for (int ct = 0; ct < 4; ++ct) nb[ct] = -bfc[ct * 32 + lm];

    const float2 ego = *(const float2*)xb;

    // ---- weights from A regs (lo lanes hold k=0..7: x,y at 0,1; f6 at 6) ----
    float wsum = 0.f;
    if (hi == 0) {
        #pragma unroll
        for (int tm = 0; tm < 4; ++tm) {
            const float dx = a0[tm].x - ego.x;
            const float dy = a0[tm].y - ego.y;
            float w = 1.0f / (sqrtf(dx * dx + dy * dy) + 1.0f);
            if (a1[tm].z == 1.0f) w *= 5.0f;   // k=6
            wls[wv][tm * 32 + lm] = w;
            wsum += w;
        }
    }
    #pragma unroll
    for (int off = 32; off > 0; off >>= 1) wsum += __shfl_xor(wsum, off);

    // ---- cvt A to f16 frags ----
    f16x8 afr[4];
    #pragma unroll
    for (int tm = 0; tm < 4; ++tm)
        afr[tm] = (f16x8){(half_t)a0[tm].x, (half_t)a0[tm].y, (half_t)a0[tm].z, (half_t)a0[tm].w,
                          (half_t)a1[tm].x, (half_t)a1[tm].y, (half_t)a1[tm].z, (half_t)a1[tm].w};

    // ---- MFMA + fold-relu weighted row-agg ----
    // D layout: col=lane&31, row=(r&3)+8*(r>>2)+4*hi
    float pacc[4] = {0.f, 0.f, 0.f, 0.f};
    #pragma unroll
    for (int tm = 0; tm < 4; ++tm) {
        float4 w4[4];
        #pragma unroll
        for (int q = 0; q < 4; ++q)
            w4[q] = *(const float4*)(&wls[wv][tm * 32 + q * 8 + hi * 4]);
        #pragma unroll
        for (int ct = 0; ct < 4; ++ct) {
            f32x16 zc = {};
            const f32x16 d = __builtin_amdgcn_mfma_f32_32x32x16_f16(afr[tm], bfr[ct], zc, 0, 0, 0);
            #pragma unroll
            for (int r = 0; r < 16; ++r)
                pacc[ct] = fmaf(w4[r >> 2][r & 3], fmaxf(d[r], nb[ct]), pacc[ct]);
        }
    }

    // ---- combine k-octet halves, store partials ----
    #pragma unroll
    for (int ct = 0; ct < 4; ++ct) pacc[ct] += __shfl_xor(pacc[ct], 32);
    if (hi == 0) {
        float* pp = p_ws + ((size_t)b * 2 + hf) * 128;
        #pragma unroll
        for (int ct = 0; ct < 4; ++ct) pp[ct * 32 + lm] = pacc[ct];
        if (lane == 0) s_ws[b * 2 + hf] = wsum;
    }
}

__global__ __launch_bounds__(256)
__attribute__((amdgpu_waves_per_eu(4, 4)))
void out_kernel(
    const float* __restrict__ p_ws,  // [4096][2][128]
    const float* __restrict__ s_ws,  // [4096][2]
    const float* __restrict__ bfc,   // [128]
    const float* __restrict__ Wagg,  // [128,128]
    const float* __restrict__ bagg,  // [128]
    float* __restrict__ out)         // [4096,128]
{
    const int t    = threadIdx.x;
    const int lane = t & 63;
    const int wv   = t >> 6;
    const int j    = blockIdx.x * 4 + wv;  // 0..2047
    const int mt   = j >> 3;               // batch tile (16 rows)
    const int ct   = j & 7;                // col tile (16 cols)
    const int lr   = lane & 15;
    const int lq   = lane >> 4;

    const int brow = mt * 16 + lr;
    const float2 s2 = *(const float2*)(s_ws + brow * 2);
    const float inv = 1.0f / (s2.x + s2.y + 1e-10f);

    const int col = ct * 16 + lr;
    const float bb = bagg[col];
    f32x4 acc = (f32x4){bb, bb, bb, bb};

    const float* pbase = p_ws + (size_t)brow * 256;
    const float* wrow  = Wagg + (size_t)col * 128;

    #pragma unroll
    for (int kk = 0; kk < 4; ++kk) {
        const int k0 = kk * 32 + lq * 8;
        const float4 p00 = *(const float4*)(pbase + k0);
        const float4 p01 = *(const float4*)(pbase + k0 + 4);
        const float4 p10 = *(const float4*)(pbase + 128 + k0);
        const float4 p11 = *(const float4*)(pbase + 128 + k0 + 4);
        const float4 bf0 = *(const float4*)(bfc + k0);
        const float4 bf1 = *(const float4*)(bfc + k0 + 4);
        // e = relu((p0+p1)*inv + bfc)  (renorm + bias + relu fused)
        const f16x8 afr = (f16x8){
            (half_t)fmaxf(fmaf(p00.x + p10.x, inv, bf0.x), 0.f),
            (half_t)fmaxf(fmaf(p00.y + p10.y, inv, bf0.y), 0.f),
            (half_t)fmaxf(fmaf(p00.z + p10.z, inv, bf0.z), 0.f),
            (half_t)fmaxf(fmaf(p00.w + p10.w, inv, bf0.w), 0.f),
            (half_t)fmaxf(fmaf(p01.x + p11.x, inv, bf1.x), 0.f),
            (half_t)fmaxf(fmaf(p01.y + p11.y, inv, bf1.y), 0.f),
            (half_t)fmaxf(fmaf(p01.z + p11.z, inv, bf1.z), 0.f),
            (half_t)fmaxf(fmaf(p01.w + p11.w, inv, bf1.w), 0.f)};
        const float4 wg0 = *(const float4*)(wrow + k0);
        const float4 wg1 = *(const float4*)(wrow + k0 + 4);
        const f16x8 bfr = (f16x8){(half_t)wg0.x, (half_t)wg0.y, (half_t)wg0.z, (half_t)wg0.w,
                                  (half_t)wg1.x, (half_t)wg1.y, (half_t)wg1.z, (half_t)wg1.w};
        acc = __builtin_amdgcn_mfma_f32_16x16x32_f16(afr, bfr, acc, 0, 0, 0);
    }

    // D: col=lane&15, row=lq*4+jj
    #pragma unroll
    for (int jj = 0; jj < 4; ++jj)
        out[(size_t)(mt * 16 + lq * 4 + jj) * 128 + col] = acc[jj];
}

extern "C" void kernel_launch(void* const* d_in, const int* in_sizes, int n_in,
                              void* d_out, int out_size, void* d_ws, size_t ws_size,
                              hipStream_t stream) {
    const float* x    = (const float*)d_in[0];
    const float* Wfc  = (const float*)d_in[1];
    const float* bfc  = (const float*)d_in[2];
    const float* Wagg = (const float*)d_in[3];
    const float* bagg = (const float*)d_in[4];
    float* out = (float*)d_out;

    float* p_ws = (float*)d_ws;                 // 4096*256 f32 = 4 MB
    float* s_ws = p_ws + (size_t)4096 * 256;    // 4096*2 f32

    agg_kernel<<<dim3(2048), dim3(256), 0, stream>>>(x, Wfc, bfc, p_ws, s_ws);
    out_kernel<<<dim3(512), dim3(256), 0, stream>>>(p_ws, s_ws, bfc, Wagg, bagg, out);
}